// Round 7
// baseline (325.896 us; speedup 1.0000x reference)
//
#include <hip/hip_runtime.h>
#include <math.h>

// Chamfer distance, fused sweep with packed-fp32 (v_pk_fma_f32) math.
// B=16, N=2048 samp, M=8192 ref, fp32.
#define BB 16
#define NN 2048
#define MM 8192

#define BLK 256
#define R 4                    // refs resident per lane (keeps VGPR ~45 for max occupancy)
#define G (BLK * R)            // 1024 refs per block
#define YS (MM / G)            // 8 ref slices
#define QCH 64                 // queries per block
#define ZS (NN / QCH)          // 32 query slices
#define QPH 16                 // queries per phase (tqbuf = 16 KB)
#define PHASES (QCH / QPH)     // 4

typedef float v2f __attribute__((ext_vector_type(2)));

static __device__ __forceinline__ v2f v2_splat(float s) { v2f r; r.x = s; r.y = s; return r; }
static __device__ __forceinline__ v2f v2_fma(v2f a, v2f b, v2f c) {
#if __has_builtin(__builtin_elementwise_fma)
    return __builtin_elementwise_fma(a, b, c);   // -> v_pk_fma_f32 on gfx950
#else
    v2f r; r.x = fmaf(a.x, b.x, c.x); r.y = fmaf(a.y, b.y, c.y); return r;
#endif
}

// ws layout (16B-aligned):
//   ref4    : float4[BB*MM]      (-2x,-2y,-2z,||p||^2)            2 MB
//   samp_pk : float4[BB*NN]      pair-SoA: (x0,x1,y0,y1|z0,z1,q0,q1)  0.5 MB
//   ws2     : uint[BB*MM]        ref->samp mins (atomic, init +inf)   0.5 MB
//   ws1p    : float[YS][BB*NN]   samp->ref per-slice mins (plain st)  1 MB

__global__ void __launch_bounds__(BLK) prep_kernel(const float* __restrict__ ref,
                                                   const float* __restrict__ samp,
                                                   float4* __restrict__ ref4,
                                                   float4* __restrict__ samp_pk,
                                                   unsigned int* __restrict__ ws2) {
    int i = blockIdx.x * blockDim.x + threadIdx.x;
    const int PM = BB * MM;
    const int PPAIR = BB * NN / 2;
    if (i < PM) {
        float p1 = ref[(size_t)i * 3 + 0], p2 = ref[(size_t)i * 3 + 1], p3 = ref[(size_t)i * 3 + 2];
        float q = fmaf(p1, p1, fmaf(p2, p2, p3 * p3));
        ref4[i] = make_float4(-2.f * p1, -2.f * p2, -2.f * p3, q);
        ws2[i] = 0x7F800000u;                              // +inf
    } else if (i < PM + PPAIR) {
        int k = i - PM;                                    // global query-pair index
        const float* s0 = samp + (size_t)k * 6;
        float x0 = s0[0], y0 = s0[1], z0 = s0[2];
        float x1 = s0[3], y1 = s0[4], z1 = s0[5];
        float w0 = fmaf(x0, x0, fmaf(y0, y0, z0 * z0));
        float w1 = fmaf(x1, x1, fmaf(y1, y1, z1 * z1));
        samp_pk[(size_t)k * 2 + 0] = make_float4(x0, x1, y0, y1);
        samp_pk[(size_t)k * 2 + 1] = make_float4(z0, z1, w0, w1);
    }
}

// grid = (B, YS, ZS) = (16, 8, 32) = 4096 blocks; ~7 blocks/CU.
// Block: 1024 refs in VGPRs (4/lane); streams 64 queries (pairs, packed fp32)
// in 4 phases of 16. Query-dir partials -> LDS -> per-y-slice plain store.
// Ref-dir mins -> one atomicMin per ref per block.
__global__ void __launch_bounds__(BLK, 7) sweep_kernel(const float4* __restrict__ ref4,
                                                       const float4* __restrict__ samp_pk,
                                                       unsigned int* __restrict__ ws2,
                                                       float* __restrict__ ws1p) {
    __shared__ v2f tqbuf[(QPH / 2) * BLK];                 // [pair][tid], 16 KB
    const int b = blockIdx.x;
    const int lane = threadIdx.x & 63;
    const int wv = threadIdx.x >> 6;                       // 0..3
    const int refbase = blockIdx.y * G + wv * (64 * R);

    const float4* rp = ref4 + (size_t)b * MM + refbase;
    float px[R], py[R], pz[R], pp[R], mref[R];
#pragma unroll
    for (int r = 0; r < R; ++r) {
        float4 v = rp[r * 64 + lane];                      // coalesced dwordx4
        px[r] = v.x; py[r] = v.y; pz[r] = v.z; pp[r] = v.w;
        mref[r] = INFINITY;
    }

    const int q0 = blockIdx.z * QCH;
    // float4 index for query q (even): b*NN + q   (2 float4 per pair)
    const float4* qt = samp_pk + (size_t)b * NN + q0;
    float* w1 = ws1p + (size_t)blockIdx.y * (BB * NN) + (size_t)b * NN + q0;

    for (int ph = 0; ph < PHASES; ++ph) {
        const float4* qp = qt + ph * QPH;                  // QPH/2 pairs = QPH float4s

        float4 a = qp[0], c = qp[1];                       // prefetched pair
#pragma unroll
        for (int j = 0; j < QPH / 2; ++j) {
            float4 an, cn;
            if (j + 1 < QPH / 2) { an = qp[2 * j + 2]; cn = qp[2 * j + 3]; }
            v2f qx; qx.x = a.x; qx.y = a.y;
            v2f qy; qy.x = a.z; qy.y = a.w;
            v2f qz; qz.x = c.x; qz.y = c.y;
            v2f qw; qw.x = c.z; qw.y = c.w;
            v2f t[R];
#pragma unroll
            for (int r = 0; r < R; ++r) {
                v2f s = v2_fma(v2_splat(px[r]), qx, v2_splat(pp[r]));
                s = v2_fma(v2_splat(py[r]), qy, s);
                s = v2_fma(v2_splat(pz[r]), qz, s);
                t[r] = s + qw;                             // full d2 (pk_add)
            }
#pragma unroll
            for (int r = 0; r < R; ++r)
                mref[r] = fminf(mref[r], fminf(t[r].x, t[r].y));   // v_min3
            v2f o;
            o.x = fminf(fminf(t[0].x, t[1].x), fminf(t[2].x, t[3].x));
            o.y = fminf(fminf(t[0].y, t[1].y), fminf(t[2].y, t[3].y));
            tqbuf[j * BLK + threadIdx.x] = o;              // ds_write_b64
            a = an; c = cn;
        }
        __syncthreads();

        // block-min per query: wave wv reduces pairs jp = wv*2 .. wv*2+1
#pragma unroll
        for (int jj = 0; jj < (QPH / 2) / 4; ++jj) {
            const int jp = wv * ((QPH / 2) / 4) + jj;
            const v2f* s2 = tqbuf + jp * BLK;
            v2f v0 = s2[lane], v1 = s2[lane + 64], v2_ = s2[lane + 128], v3 = s2[lane + 192];
            float m0 = fminf(fminf(v0.x, v1.x), fminf(v2_.x, v3.x));
            float m1 = fminf(fminf(v0.y, v1.y), fminf(v2_.y, v3.y));
#pragma unroll
            for (int s = 32; s > 0; s >>= 1) {
                m0 = fminf(m0, __shfl_xor(m0, s));
                m1 = fminf(m1, __shfl_xor(m1, s));
            }
            if (lane == 0) {
                float2 st; st.x = m0; st.y = m1;
                *(float2*)(w1 + ph * QPH + 2 * jp) = st;   // plain store, 8B
            }
        }
        __syncthreads();
    }

    unsigned int* w2 = ws2 + (size_t)b * MM + refbase;
#pragma unroll
    for (int r = 0; r < R; ++r)
        atomicMin(&w2[r * 64 + lane], __float_as_uint(fmaxf(mref[r], 0.f)));
}

// Final reduce. grid = B, block = 1024.
#define BLKR 1024
__global__ void __launch_bounds__(BLKR) reduce_kernel(const float* __restrict__ ws1p,
                                                      const unsigned int* __restrict__ ws2,
                                                      float* __restrict__ out) {
    const int b = blockIdx.x;
    const int tid = threadIdx.x;

    float sd1 = 0.f, sr1 = 0.f;
    for (int i = tid; i < NN; i += BLKR) {
        float m = INFINITY;
#pragma unroll
        for (int y = 0; y < YS; ++y)
            m = fminf(m, ws1p[(size_t)y * (BB * NN) + (size_t)b * NN + i]);
        float v = fmaxf(m, 0.f);                           // d2 already includes qw
        sd1 += v;
        sr1 += sqrtf(v);
    }
    float sd2 = 0.f, sr2 = 0.f;
    for (int i = tid; i < MM; i += BLKR) {
        float v = __uint_as_float(ws2[(size_t)b * MM + i]);  // already >= 0
        sd2 += v;
        sr2 += sqrtf(v);
    }

    __shared__ float4 red[BLKR];
    red[tid] = make_float4(sd1, sr1, sd2, sr2);
    __syncthreads();
    for (int s = BLKR / 2; s > 0; s >>= 1) {
        if (tid < s) {
            red[tid].x += red[tid + s].x;
            red[tid].y += red[tid + s].y;
            red[tid].z += red[tid + s].z;
            red[tid].w += red[tid + s].w;
        }
        __syncthreads();
    }
    if (tid == 0) {
        float4 r = red[0];
        out[b]      = (r.y * (1.0f / NN) + r.w * (1.0f / MM)) * 0.5f;  // cd_p
        out[BB + b] = r.x * (1.0f / NN) + r.z * (1.0f / MM);           // cd_t
    }
}

extern "C" void kernel_launch(void* const* d_in, const int* in_sizes, int n_in,
                              void* d_out, int out_size, void* d_ws, size_t ws_size,
                              hipStream_t stream) {
    const float* ref  = (const float*)d_in[0];   // [B, M, 3]
    const float* samp = (const float*)d_in[1];   // [B, N, 3]
    float* out = (float*)d_out;                  // [cd_p[16], cd_t[16]]

    float4* ref4    = (float4*)d_ws;                                 // BB*MM
    float4* samp_pk = ref4 + (size_t)BB * MM;                        // BB*NN
    unsigned int* ws2 = (unsigned int*)(samp_pk + (size_t)BB * NN);  // BB*MM
    float* ws1p = (float*)(ws2 + (size_t)BB * MM);                   // YS*BB*NN

    const int P = BB * MM + BB * NN / 2;
    prep_kernel<<<(P + BLK - 1) / BLK, BLK, 0, stream>>>(ref, samp, ref4, samp_pk, ws2);

    dim3 gs(BB, YS, ZS);   // (16, 8, 32) = 4096 blocks
    sweep_kernel<<<gs, BLK, 0, stream>>>(ref4, samp_pk, ws2, ws1p);

    reduce_kernel<<<BB, BLKR, 0, stream>>>(ws1p, ws2, out);
}

// Round 8
// 100.041 us; speedup vs baseline: 3.2576x; 3.2576x over previous
//
#include <hip/hip_runtime.h>
#include <math.h>

// Chamfer distance, fused sweep with packed-fp32 (v_pk_fma_f32) math.
// B=16, N=2048 samp, M=8192 ref, fp32.
#define BB 16
#define NN 2048
#define MM 8192

#define BLK 256
#define R 4                    // refs resident per lane
#define G (BLK * R)            // 1024 refs per block
#define YS (MM / G)            // 8 ref slices
#define QCH 32                 // queries per block
#define ZS (NN / QCH)          // 64 query slices
#define QPH 16                 // queries per phase (tqbuf = 16 KB)
#define PHASES (QCH / QPH)     // 2

typedef float v2f __attribute__((ext_vector_type(2)));

static __device__ __forceinline__ v2f v2_splat(float s) { v2f r; r.x = s; r.y = s; return r; }
static __device__ __forceinline__ v2f v2_fma(v2f a, v2f b, v2f c) {
#if __has_builtin(__builtin_elementwise_fma)
    return __builtin_elementwise_fma(a, b, c);   // -> v_pk_fma_f32 on gfx950
#else
    v2f r; r.x = fmaf(a.x, b.x, c.x); r.y = fmaf(a.y, b.y, c.y); return r;
#endif
}

// ws layout (16B-aligned):
//   ref4    : float4[BB*MM]      (-2x,-2y,-2z,||p||^2)                2 MB
//   samp_pk : float4[BB*NN]      pair-SoA: (x0,x1,y0,y1|z0,z1,q0,q1)  0.5 MB
//   ws2     : uint[BB*MM]        ref->samp mins (atomic, init +inf)   0.5 MB
//   ws1p    : float[YS][BB*NN]   samp->ref per-slice mins (plain st)  1 MB

__global__ void __launch_bounds__(BLK) prep_kernel(const float* __restrict__ ref,
                                                   const float* __restrict__ samp,
                                                   float4* __restrict__ ref4,
                                                   float4* __restrict__ samp_pk,
                                                   unsigned int* __restrict__ ws2) {
    int i = blockIdx.x * blockDim.x + threadIdx.x;
    const int PM = BB * MM;
    const int PPAIR = BB * NN / 2;
    if (i < PM) {
        float p1 = ref[(size_t)i * 3 + 0], p2 = ref[(size_t)i * 3 + 1], p3 = ref[(size_t)i * 3 + 2];
        float q = fmaf(p1, p1, fmaf(p2, p2, p3 * p3));
        ref4[i] = make_float4(-2.f * p1, -2.f * p2, -2.f * p3, q);
        ws2[i] = 0x7F800000u;                              // +inf
    } else if (i < PM + PPAIR) {
        int k = i - PM;                                    // global query-pair index
        const float* s0 = samp + (size_t)k * 6;
        float x0 = s0[0], y0 = s0[1], z0 = s0[2];
        float x1 = s0[3], y1 = s0[4], z1 = s0[5];
        float w0 = fmaf(x0, x0, fmaf(y0, y0, z0 * z0));
        float w1 = fmaf(x1, x1, fmaf(y1, y1, z1 * z1));
        samp_pk[(size_t)k * 2 + 0] = make_float4(x0, x1, y0, y1);
        samp_pk[(size_t)k * 2 + 1] = make_float4(z0, z1, w0, w1);
    }
}

// grid = (B, YS, ZS) = (16, 8, 64) = 8192 blocks; 5 waves/SIMD (LDS 16 KB, VGPR<=102).
// Block: 1024 refs in VGPRs (4/lane); streams 32 queries (pairs, packed fp32)
// in 2 phases of 16. Query-dir partials -> LDS -> per-y-slice plain store.
// Ref-dir mins -> one atomicMin per ref per block.
__global__ void __launch_bounds__(BLK, 5) sweep_kernel(const float4* __restrict__ ref4,
                                                       const float4* __restrict__ samp_pk,
                                                       unsigned int* __restrict__ ws2,
                                                       float* __restrict__ ws1p) {
    __shared__ v2f tqbuf[(QPH / 2) * BLK];                 // [pair][tid], 16 KB
    const int b = blockIdx.x;
    const int lane = threadIdx.x & 63;
    const int wv = threadIdx.x >> 6;                       // 0..3
    const int refbase = blockIdx.y * G + wv * (64 * R);

    const float4* rp = ref4 + (size_t)b * MM + refbase;
    float px[R], py[R], pz[R], pp[R], mref[R];
#pragma unroll
    for (int r = 0; r < R; ++r) {
        float4 v = rp[r * 64 + lane];                      // coalesced dwordx4
        px[r] = v.x; py[r] = v.y; pz[r] = v.z; pp[r] = v.w;
        mref[r] = INFINITY;
    }

    const int q0 = blockIdx.z * QCH;
    const float4* qt = samp_pk + (size_t)b * NN + q0;      // 2 float4 per pair
    float* w1 = ws1p + (size_t)blockIdx.y * (BB * NN) + (size_t)b * NN + q0;

    for (int ph = 0; ph < PHASES; ++ph) {
        const float4* qp = qt + ph * QPH;                  // QPH/2 = 8 pairs

#pragma unroll 4
        for (int j = 0; j < QPH / 2; ++j) {
            float4 a = qp[2 * j];                          // (x0,x1,y0,y1)
            float4 c = qp[2 * j + 1];                      // (z0,z1,w0,w1)
            v2f qx; qx.x = a.x; qx.y = a.y;
            v2f qy; qy.x = a.z; qy.y = a.w;
            v2f qz; qz.x = c.x; qz.y = c.y;
            v2f qw; qw.x = c.z; qw.y = c.w;
            v2f t[R];
#pragma unroll
            for (int r = 0; r < R; ++r) {
                v2f s = v2_fma(v2_splat(px[r]), qx, v2_splat(pp[r]));
                s = v2_fma(v2_splat(py[r]), qy, s);
                s = v2_fma(v2_splat(pz[r]), qz, s);
                t[r] = s + qw;                             // full d2 (v_pk_add_f32)
            }
#pragma unroll
            for (int r = 0; r < R; ++r)
                mref[r] = fminf(fminf(mref[r], t[r].x), t[r].y);   // v_min3
            v2f o;
            o.x = fminf(fminf(t[0].x, t[1].x), fminf(t[2].x, t[3].x));
            o.y = fminf(fminf(t[0].y, t[1].y), fminf(t[2].y, t[3].y));
            tqbuf[j * BLK + threadIdx.x] = o;              // ds_write_b64
        }
        __syncthreads();

        // block-min per query: wave wv reduces pairs jp = wv*2 .. wv*2+1
#pragma unroll
        for (int jj = 0; jj < (QPH / 2) / 4; ++jj) {
            const int jp = wv * ((QPH / 2) / 4) + jj;
            const v2f* s2 = tqbuf + jp * BLK;
            v2f v0 = s2[lane], v1 = s2[lane + 64], v2_ = s2[lane + 128], v3 = s2[lane + 192];
            float m0 = fminf(fminf(v0.x, v1.x), fminf(v2_.x, v3.x));
            float m1 = fminf(fminf(v0.y, v1.y), fminf(v2_.y, v3.y));
#pragma unroll
            for (int s = 32; s > 0; s >>= 1) {
                m0 = fminf(m0, __shfl_xor(m0, s));
                m1 = fminf(m1, __shfl_xor(m1, s));
            }
            if (lane == 0) {
                float2 st; st.x = m0; st.y = m1;
                *(float2*)(w1 + ph * QPH + 2 * jp) = st;   // plain store, 8B
            }
        }
        __syncthreads();
    }

    unsigned int* w2 = ws2 + (size_t)b * MM + refbase;
#pragma unroll
    for (int r = 0; r < R; ++r)
        atomicMin(&w2[r * 64 + lane], __float_as_uint(fmaxf(mref[r], 0.f)));
}

// Final reduce. grid = B, block = 1024.
#define BLKR 1024
__global__ void __launch_bounds__(BLKR) reduce_kernel(const float* __restrict__ ws1p,
                                                      const unsigned int* __restrict__ ws2,
                                                      float* __restrict__ out) {
    const int b = blockIdx.x;
    const int tid = threadIdx.x;

    float sd1 = 0.f, sr1 = 0.f;
    for (int i = tid; i < NN; i += BLKR) {
        float m = INFINITY;
#pragma unroll
        for (int y = 0; y < YS; ++y)
            m = fminf(m, ws1p[(size_t)y * (BB * NN) + (size_t)b * NN + i]);
        float v = fmaxf(m, 0.f);                           // d2 already includes qw
        sd1 += v;
        sr1 += sqrtf(v);
    }
    float sd2 = 0.f, sr2 = 0.f;
    for (int i = tid; i < MM; i += BLKR) {
        float v = __uint_as_float(ws2[(size_t)b * MM + i]);  // already >= 0
        sd2 += v;
        sr2 += sqrtf(v);
    }

    __shared__ float4 red[BLKR];
    red[tid] = make_float4(sd1, sr1, sd2, sr2);
    __syncthreads();
    for (int s = BLKR / 2; s > 0; s >>= 1) {
        if (tid < s) {
            red[tid].x += red[tid + s].x;
            red[tid].y += red[tid + s].y;
            red[tid].z += red[tid + s].z;
            red[tid].w += red[tid + s].w;
        }
        __syncthreads();
    }
    if (tid == 0) {
        float4 r = red[0];
        out[b]      = (r.y * (1.0f / NN) + r.w * (1.0f / MM)) * 0.5f;  // cd_p
        out[BB + b] = r.x * (1.0f / NN) + r.z * (1.0f / MM);           // cd_t
    }
}

extern "C" void kernel_launch(void* const* d_in, const int* in_sizes, int n_in,
                              void* d_out, int out_size, void* d_ws, size_t ws_size,
                              hipStream_t stream) {
    const float* ref  = (const float*)d_in[0];   // [B, M, 3]
    const float* samp = (const float*)d_in[1];   // [B, N, 3]
    float* out = (float*)d_out;                  // [cd_p[16], cd_t[16]]

    float4* ref4    = (float4*)d_ws;                                 // BB*MM
    float4* samp_pk = ref4 + (size_t)BB * MM;                        // BB*NN
    unsigned int* ws2 = (unsigned int*)(samp_pk + (size_t)BB * NN);  // BB*MM
    float* ws1p = (float*)(ws2 + (size_t)BB * MM);                   // YS*BB*NN

    const int P = BB * MM + BB * NN / 2;
    prep_kernel<<<(P + BLK - 1) / BLK, BLK, 0, stream>>>(ref, samp, ref4, samp_pk, ws2);

    dim3 gs(BB, YS, ZS);   // (16, 8, 64) = 8192 blocks
    sweep_kernel<<<gs, BLK, 0, stream>>>(ref4, samp_pk, ws2, ws1p);

    reduce_kernel<<<BB, BLKR, 0, stream>>>(ws1p, ws2, out);
}